// Round 4
// baseline (175.001 us; speedup 1.0000x reference)
//
#include <hip/hip_runtime.h>
#include <math.h>

#define DD 1024
#define HH1 4096
#define HH2 4096

typedef __attribute__((ext_vector_type(8))) short bf16x8;
typedef __attribute__((ext_vector_type(4))) float f32x4;
typedef unsigned short ushort_t;

// fast-path ws layout (bytes) — total exactly 42,008,576:
//   [0)        u0 (4096 f32)   -- overlaid by P (512 f32) after k0a
//   [16384)    q  (4096 f32)
//   [32768)    cv (4096 f32)
//   [49152)    cd (4096 f32)
//   [65536)    A' = bf16(W2 .* s)  4096x4096 (33554432 B)
//   [33619968) B' = bf16(W1^T)     1024x4096 ( 8388608 B)
#define WS_FAST_BYTES 42008576ull
#define K4_LDS_BYTES 131072

__device__ inline void wave_reduce2(float& a, float& b) {
  #pragma unroll
  for (int off = 32; off > 0; off >>= 1) {
    a += __shfl_down(a, off, 64);
    b += __shfl_down(b, off, 64);
  }
}

// fp32 -> bf16 RNE
__device__ inline unsigned int f2b(float f) {
  union { float f; unsigned int u; } v; v.f = f;
  return (v.u + 0x7FFFu + ((v.u >> 16) & 1u)) >> 16;
}
__device__ inline unsigned int pack2(float a, float b) {
  return f2b(a) | (f2b(b) << 16);
}

// async global->LDS, 16 B per lane; lds dst = wave-uniform base + lane*16
__device__ inline void gl_lds16(const void* g, void* l) {
  __builtin_amdgcn_global_load_lds(
      (const __attribute__((address_space(1))) unsigned int*)g,
      (__attribute__((address_space(3))) unsigned int*)l, 16, 0, 0);
}

// kA3: fused layer-1 + W1 transpose-convert (R3-proven). Block = 16 rows.
#define TP2 1032
__global__ __launch_bounds__(256) void kA3_l1t(
    const float* __restrict__ W1, const float* __restrict__ x,
    const float* __restrict__ b1, float* __restrict__ u0,
    float* __restrict__ q, ushort_t* __restrict__ Bp) {
  __shared__ __align__(16) ushort_t T[16 * TP2];  // 33 KB
  const int tid = threadIdx.x;
  const int h0 = blockIdx.x * 16;
  const int r = tid >> 4;          // 0..15 row within block
  const int c = tid & 15;          // 16 threads per row
  const float4* rp = (const float4*)(W1 + (size_t)(h0 + r) * DD);
  const float4* x4 = (const float4*)x;
  float dot = 0.f, sq = 0.f;
  #pragma unroll
  for (int j = 0; j < 16; ++j) {
    const int f = c + j * 16;      // float4 col index 0..255
    float4 wv = rp[f];
    float4 xv = x4[f];
    dot += wv.x * xv.x + wv.y * xv.y + wv.z * xv.z + wv.w * xv.w;
    sq  += wv.x * wv.x + wv.y * wv.y + wv.z * wv.z + wv.w * wv.w;
    uint2 pk;
    pk.x = pack2(wv.x, wv.y);
    pk.y = pack2(wv.z, wv.w);
    *(uint2*)&T[r * TP2 + f * 4] = pk;
  }
  #pragma unroll
  for (int off = 8; off > 0; off >>= 1) {
    dot += __shfl_down(dot, off, 16);
    sq  += __shfl_down(sq, off, 16);
  }
  if (c == 0) {
    float a0 = dot + b1[h0 + r];
    float u = tanhf(a0);
    float s = 1.f - u * u;
    u0[h0 + r] = u;
    q[h0 + r] = -2.f * u * s * sq;
  }
  __syncthreads();
  // transpose out: thread handles i-cols {ip, ip+1} for rep 0,1
  #pragma unroll
  for (int rep = 0; rep < 2; ++rep) {
    const int ip = rep * 512 + tid * 2;
    #pragma unroll
    for (int cg = 0; cg < 2; ++cg) {
      unsigned int R[8];
      #pragma unroll
      for (int r8 = 0; r8 < 8; ++r8)
        R[r8] = *(const unsigned int*)&T[(cg * 8 + r8) * TP2 + ip];
      unsigned int oa[4], ob[4];
      #pragma unroll
      for (int k2 = 0; k2 < 4; ++k2) {
        oa[k2] = (R[2 * k2] & 0xffffu) | (R[2 * k2 + 1] << 16);
        ob[k2] = (R[2 * k2] >> 16) | (R[2 * k2 + 1] & 0xffff0000u);
      }
      *(uint4*)(Bp + (size_t)ip * HH1 + h0 + cg * 8) = *(const uint4*)oa;
      *(uint4*)(Bp + (size_t)(ip + 1) * HH1 + h0 + cg * 8) = *(const uint4*)ob;
    }
  }
}

// k0a v2 (R3-proven): preloaded streaming; z/d dots, A' convert, cv/cd.
__global__ __launch_bounds__(256) void k0a_layer2conv(
    const float* __restrict__ W2, const float* __restrict__ b2,
    const float* __restrict__ W3, const float* __restrict__ u0,
    const float* __restrict__ q, ushort_t* __restrict__ Ap,
    float* __restrict__ cv, float* __restrict__ cd) {
  int g = blockIdx.x;
  int tid = threadIdx.x;
  const float4* row = (const float4*)(W2 + (size_t)g * HH1);
  const float4* u4 = (const float4*)u0;
  const float4* q4 = (const float4*)q;
  float4 w[4], u[4], qq[4];
  #pragma unroll
  for (int it = 0; it < 4; ++it) w[it] = row[tid + it * 256];
  #pragma unroll
  for (int it = 0; it < 4; ++it) u[it] = u4[tid + it * 256];
  #pragma unroll
  for (int it = 0; it < 4; ++it) qq[it] = q4[tid + it * 256];
  float zacc = 0.f, dacc = 0.f;
  #pragma unroll
  for (int it = 0; it < 4; ++it) {
    const int j = tid + it * 256;
    float4 sv;
    sv.x = 1.f - u[it].x * u[it].x;
    sv.y = 1.f - u[it].y * u[it].y;
    sv.z = 1.f - u[it].z * u[it].z;
    sv.w = 1.f - u[it].w * u[it].w;
    zacc += w[it].x * u[it].x + w[it].y * u[it].y +
            w[it].z * u[it].z + w[it].w * u[it].w;
    dacc += w[it].x * qq[it].x + w[it].y * qq[it].y +
            w[it].z * qq[it].z + w[it].w * qq[it].w;
    uint2 pk;
    pk.x = pack2(w[it].x * sv.x, w[it].y * sv.y);
    pk.y = pack2(w[it].z * sv.z, w[it].w * sv.w);
    *(uint2*)(Ap + (size_t)g * HH1 + j * 4) = pk;
  }
  wave_reduce2(zacc, dacc);
  __shared__ float lds[8];
  int lane = tid & 63, wid = tid >> 6;
  if (lane == 0) { lds[wid * 2] = zacc; lds[wid * 2 + 1] = dacc; }
  __syncthreads();
  if (tid == 0) {
    float z = lds[0] + lds[2] + lds[4] + lds[6] + b2[g];
    float d = lds[1] + lds[3] + lds[5] + lds[7];
    float v = tanhf(z);
    float t = 1.f - v * v;
    float c = W3[g] * t;
    cv[g] = c * v;
    cd[g] = c * d;
  }
}

// k4 v4: bf16 GEMM-BT M = A'·B'^T, tile 128(g) x 128(i), BK=64, 8 waves.
// Parity K-interleave: waves 0-3 compute even tiles, 4-7 odd tiles; each
// wave owns a 64x64 quadrant via 4x4 of 16x16x32 MFMA (64 acc VGPR).
// Fragment reads use the v2-PROVEN conflict-free pattern (fr=lane&15,
// chunk (kk*4+fc)^(fr&7)); v3's 32x32 frags 4-way-conflicted because
// 128 B row stride ≡ 0 mod 32 banks across 32 rows.
// Per-tile LDS traffic: 64 KB reads (4 waves) + 32 KB DMA writes = 96 KB
// vs v2's 128 KB. Quad-buffer, counted vmcnt(8), raw barriers, setprio.
// Epilogue: odd-group donates accs via LDS; even-group sums, computes
// P[block] = Σ cv[g]*M[g,i]^2.
__global__ __launch_bounds__(512) void k4_v4(
    const ushort_t* __restrict__ Ap, const ushort_t* __restrict__ Bp,
    const float* __restrict__ cv, float* __restrict__ P) {
  extern __shared__ __align__(16) char smem[];  // 4 bufs x (A 16K + B 16K)

  const int tid = threadIdx.x;
  const int lane = tid & 63;
  const int wave = tid >> 6;           // 0..7
  const int gp = wave >> 2;            // tile-parity group
  const int wq = wave & 3;             // quadrant id
  const int wm = wq >> 1, wn = wq & 1; // 64-row halves (g, i)
  const int l = blockIdx.x;            // 0..255
  const int xcd = l & 7;
  const int jj = l >> 3;
  const int g0 = (xcd * 4 + (jj & 3)) * 128;   // XCD owns 4 g-stripes
  const int i0 = (jj >> 2) * 128;

  // staging: lane fills phys chunk (lane&7) of row r0+(lane>>3);
  // source logical chunk = (lane&7)^(lane>>3)  (r0 ≡ 0 mod 8)
  const int srow = lane >> 3;
  const int lchunk = (lane & 7) ^ srow;
  const ushort_t* gA0 = Ap + (size_t)(g0 + wave * 16 + 0 + srow) * HH1 + lchunk * 8;
  const ushort_t* gA1 = Ap + (size_t)(g0 + wave * 16 + 8 + srow) * HH1 + lchunk * 8;
  const ushort_t* gB0 = Bp + (size_t)(i0 + wave * 16 + 0 + srow) * HH1 + lchunk * 8;
  const ushort_t* gB1 = Bp + (size_t)(i0 + wave * 16 + 8 + srow) * HH1 + lchunk * 8;

  // fragment addressing: v2-proven conflict-free pattern
  const int fr = lane & 15;
  const int fc = lane >> 4;
  const int rsw = fr & 7;

  f32x4 acc[4][4];
  const f32x4 zero = {0.f, 0.f, 0.f, 0.f};
  #pragma unroll
  for (int mt = 0; mt < 4; ++mt)
    #pragma unroll
    for (int nt = 0; nt < 4; ++nt) acc[mt][nt] = zero;

  // one tile = 4 calls/wave (A 16 rows, B 16 rows), 1 KB each, linear dst
  #define STAGE(tile) do {                                              \
      char* tb_ = smem + ((tile) & 3) * 32768;                          \
      const int ko_ = ((tile) & 63) * 64;                               \
      gl_lds16(gA0 + ko_, tb_ + (wave * 16 + 0) * 128 + lane * 16);     \
      gl_lds16(gA1 + ko_, tb_ + (wave * 16 + 8) * 128 + lane * 16);     \
      gl_lds16(gB0 + ko_, tb_ + 16384 + (wave * 16 + 0) * 128 + lane * 16); \
      gl_lds16(gB1 + ko_, tb_ + 16384 + (wave * 16 + 8) * 128 + lane * 16); \
    } while (0)

  STAGE(0); STAGE(1);                  // prologue: pair 0 in flight
  for (int s = 0; s < 32; ++s) {
    STAGE(2 * s + 2);                  // next pair into freed buffers
    STAGE(2 * s + 3);
    // 8 newest (pair s+1) stay in flight; pair s has landed
    asm volatile("s_waitcnt vmcnt(8)" ::: "memory");
    __builtin_amdgcn_s_barrier();
    asm volatile("" ::: "memory");
    const char* tb = smem + ((2 * s + gp) & 3) * 32768;
    #pragma unroll
    for (int kk = 0; kk < 2; ++kk) {
      const int cb = ((kk * 4 + fc) ^ rsw) * 16;
      bf16x8 af[4], bfv[4];
      #pragma unroll
      for (int mt = 0; mt < 4; ++mt)
        af[mt] = *(const bf16x8*)(tb + (wm * 64 + mt * 16 + fr) * 128 + cb);
      #pragma unroll
      for (int nt = 0; nt < 4; ++nt)
        bfv[nt] = *(const bf16x8*)(tb + 16384 + (wn * 64 + nt * 16 + fr) * 128 + cb);
      __builtin_amdgcn_s_setprio(1);
      #pragma unroll
      for (int mt = 0; mt < 4; ++mt)
        #pragma unroll
        for (int nt = 0; nt < 4; ++nt)
          acc[mt][nt] = __builtin_amdgcn_mfma_f32_16x16x32_bf16(
              af[mt], bfv[nt], acc[mt][nt], 0, 0, 0);
      __builtin_amdgcn_s_setprio(0);
    }
    asm volatile("" ::: "memory");
    __builtin_amdgcn_s_barrier();
  }
  #undef STAGE

  // drain wrap-around stages (bufs 0,1) before LDS reuse
  asm volatile("s_waitcnt vmcnt(0)" ::: "memory");
  __builtin_amdgcn_s_barrier();

  // acc exchange: odd-group wave (4+wq) -> zone wq at [64K..128K)
  char* xz = smem + 65536 + wq * 16384;
  if (gp == 1) {
    #pragma unroll
    for (int mt = 0; mt < 4; ++mt)
      #pragma unroll
      for (int nt = 0; nt < 4; ++nt)
        *(f32x4*)(xz + (mt * 4 + nt) * 1024 + lane * 16) = acc[mt][nt];
  }
  __syncthreads();
  float part = 0.f;
  if (gp == 0) {
    #pragma unroll
    for (int mt = 0; mt < 4; ++mt) {
      #pragma unroll
      for (int nt = 0; nt < 4; ++nt) {
        f32x4 v = *(const f32x4*)(xz + (mt * 4 + nt) * 1024 + lane * 16);
        acc[mt][nt][0] += v[0];
        acc[mt][nt][1] += v[1];
        acc[mt][nt][2] += v[2];
        acc[mt][nt][3] += v[3];
      }
    }
    // epilogue: part = Σ cv[g] * Σ_i M[g,i]^2
    #pragma unroll
    for (int mt = 0; mt < 4; ++mt) {
      #pragma unroll
      for (int r = 0; r < 4; ++r) {
        const int g = g0 + wm * 64 + mt * 16 + fc * 4 + r;
        const float c = cv[g];
        float ss = 0.f;
        #pragma unroll
        for (int nt = 0; nt < 4; ++nt) {
          float v = acc[mt][nt][r];
          ss += v * v;
        }
        part += c * ss;
      }
    }
    #pragma unroll
    for (int off = 32; off > 0; off >>= 1) part += __shfl_down(part, off, 64);
  }
  __syncthreads();                     // zones consumed
  if (gp == 0 && lane == 0) ((float*)smem)[wq] = part;
  __syncthreads();
  if (tid == 0) {
    float* rp = (float*)smem;
    P[l] = rp[0] + rp[1] + rp[2] + rp[3];
  }
}

// k5: out[0] = Σ cd - 2 Σ P. Plain store (no atomics, no zero-init needed).
__global__ __launch_bounds__(256) void k5_final(
    const float* __restrict__ cd, const float* __restrict__ P,
    float* __restrict__ out) {
  int tid = threadIdx.x;
  float a = 0.f;
  for (int j = tid; j < HH2; j += 256) a += cd[j];
  float b = P[tid];  // k4 grid = 256
  float v = a - 2.f * b;
  #pragma unroll
  for (int off = 32; off > 0; off >>= 1) v += __shfl_down(v, off, 64);
  __shared__ float lds[4];
  int lane = tid & 63, wid = tid >> 6;
  if (lane == 0) lds[wid] = v;
  __syncthreads();
  if (tid == 0) out[0] = lds[0] + lds[1] + lds[2] + lds[3];
}

// ---------------- fallback (fp32, ws = 64 KB only; R1-proven) ----------------

__global__ __launch_bounds__(256) void k1_slow(
    const float* __restrict__ W1, const float* __restrict__ x,
    const float* __restrict__ b1, float* __restrict__ u0,
    float* __restrict__ q, float* __restrict__ s_out,
    float* __restrict__ out) {
  int h = blockIdx.x;
  int tid = threadIdx.x;
  const float4* row = (const float4*)(W1 + (size_t)h * DD);
  const float4* x4 = (const float4*)x;
  float4 w = row[tid];
  float4 xv = x4[tid];
  float dot = w.x * xv.x + w.y * xv.y + w.z * xv.z + w.w * xv.w;
  float sq = w.x * w.x + w.y * w.y + w.z * w.z + w.w * w.w;
  wave_reduce2(dot, sq);
  __shared__ float lds[8];
  int lane = tid & 63, wid = tid >> 6;
  if (lane == 0) { lds[wid * 2] = dot; lds[wid * 2 + 1] = sq; }
  __syncthreads();
  if (tid == 0) {
    float dsum = lds[0] + lds[2] + lds[4] + lds[6];
    float rsum = lds[1] + lds[3] + lds[5] + lds[7];
    float a0 = dsum + b1[h];
    float u = tanhf(a0);
    float s = 1.f - u * u;
    u0[h] = u;
    s_out[h] = s;
    q[h] = -2.f * u * s * rsum;
    if (h == 0) out[0] = 0.f;
  }
}

__global__ __launch_bounds__(256) void k2_slow(
    const float* __restrict__ W2, const float* __restrict__ b2,
    const float* __restrict__ W3, const float* __restrict__ u0,
    const float* __restrict__ q, float* __restrict__ cv,
    float* __restrict__ out) {
  int g = blockIdx.x;
  int tid = threadIdx.x;
  const float4* row = (const float4*)(W2 + (size_t)g * HH1);
  const float4* u4 = (const float4*)u0;
  const float4* q4 = (const float4*)q;
  float zacc = 0.f, dacc = 0.f;
  for (int j = tid; j < HH1 / 4; j += 256) {
    float4 w = row[j];
    float4 u = u4[j];
    float4 qq = q4[j];
    zacc += w.x * u.x + w.y * u.y + w.z * u.z + w.w * u.w;
    dacc += w.x * qq.x + w.y * qq.y + w.z * qq.z + w.w * qq.w;
  }
  wave_reduce2(zacc, dacc);
  __shared__ float lds[8];
  int lane = tid & 63, wid = tid >> 6;
  if (lane == 0) { lds[wid * 2] = zacc; lds[wid * 2 + 1] = dacc; }
  __syncthreads();
  if (tid == 0) {
    float z = lds[0] + lds[2] + lds[4] + lds[6] + b2[g];
    float d = lds[1] + lds[3] + lds[5] + lds[7];
    float v = tanhf(z);
    float t = 1.f - v * v;
    float c = W3[g] * t;
    cv[g] = c * v;
    atomicAdd(out, c * d);
  }
}

__global__ __launch_bounds__(256) void k4_slow(
    const float* __restrict__ W2, const float* __restrict__ W1,
    const float* __restrict__ s, const float* __restrict__ cv,
    float* __restrict__ out) {
  __shared__ float As[32][68];
  __shared__ float Bs[32][68];
  int tid = threadIdx.x;
  int g0 = blockIdx.y * 64;
  int i0 = blockIdx.x * 64;
  int tr = (tid / 16) * 4;
  int tc = (tid % 16) * 4;
  float acc[4][4] = {};
  for (int k0 = 0; k0 < HH1; k0 += 32) {
    for (int ll = tid; ll < (64 * 32 / 4); ll += 256) {
      int row = ll / 8;
      int c4 = ll % 8;
      float4 w = *(const float4*)(W2 + (size_t)(g0 + row) * HH1 + k0 + c4 * 4);
      float4 sv = *(const float4*)(s + k0 + c4 * 4);
      As[c4 * 4 + 0][row] = w.x * sv.x;
      As[c4 * 4 + 1][row] = w.y * sv.y;
      As[c4 * 4 + 2][row] = w.z * sv.z;
      As[c4 * 4 + 3][row] = w.w * sv.w;
    }
    for (int ll = tid; ll < (32 * 64 / 4); ll += 256) {
      int row = ll / 16;
      int c4 = ll % 16;
      float4 w = *(const float4*)(W1 + (size_t)(k0 + row) * DD + i0 + c4 * 4);
      *(float4*)&Bs[row][c4 * 4] = w;
    }
    __syncthreads();
    #pragma unroll
    for (int k = 0; k < 32; ++k) {
      float4 av = *(const float4*)&As[k][tr];
      float4 bv = *(const float4*)&Bs[k][tc];
      float a_[4] = {av.x, av.y, av.z, av.w};
      float b_[4] = {bv.x, bv.y, bv.z, bv.w};
      #pragma unroll
      for (int r = 0; r < 4; ++r)
        #pragma unroll
        for (int c = 0; c < 4; ++c)
          acc[r][c] += a_[r] * b_[c];
    }
    __syncthreads();
  }
  float contrib = 0.f;
  #pragma unroll
  for (int r = 0; r < 4; ++r) {
    float ss = acc[r][0] * acc[r][0] + acc[r][1] * acc[r][1] +
               acc[r][2] * acc[r][2] + acc[r][3] * acc[r][3];
    contrib += cv[g0 + tr + r] * ss;
  }
  #pragma unroll
  for (int off = 32; off > 0; off >>= 1) contrib += __shfl_down(contrib, off, 64);
  __shared__ float red[4];
  int lane = tid & 63, wid = tid >> 6;
  if (lane == 0) red[wid] = contrib;
  __syncthreads();
  if (tid == 0) atomicAdd(out, -2.f * (red[0] + red[1] + red[2] + red[3]));
}

extern "C" void kernel_launch(void* const* d_in, const int* in_sizes, int n_in,
                              void* d_out, int out_size, void* d_ws, size_t ws_size,
                              hipStream_t stream) {
  const float* x  = (const float*)d_in[0];
  const float* W1 = (const float*)d_in[1];
  const float* b1 = (const float*)d_in[2];
  const float* W2 = (const float*)d_in[3];
  const float* b2 = (const float*)d_in[4];
  const float* W3 = (const float*)d_in[5];
  // b3 (d_in[6]) vanishes under the Laplacian.
  float* out = (float*)d_out;
  float* ws = (float*)d_ws;

  if (ws_size >= WS_FAST_BYTES) {
    float* u0 = ws;              // overlaid by P after k0a completes
    float* q  = ws + 4096;
    float* cv = ws + 8192;
    float* cd = ws + 12288;
    float* P  = ws;              // 256 floats, k4 -> k5
    ushort_t* Ap = (ushort_t*)((char*)d_ws + 65536);
    ushort_t* Bp = (ushort_t*)((char*)d_ws + 33619968);
    hipFuncSetAttribute((const void*)k4_v4,
                        hipFuncAttributeMaxDynamicSharedMemorySize,
                        K4_LDS_BYTES);
    hipLaunchKernelGGL(kA3_l1t, dim3(256), dim3(256), 0, stream,
                       W1, x, b1, u0, q, Bp);
    hipLaunchKernelGGL(k0a_layer2conv, dim3(HH2), dim3(256), 0, stream,
                       W2, b2, W3, u0, q, Ap, cv, cd);
    hipLaunchKernelGGL(k4_v4, dim3(256), dim3(512), K4_LDS_BYTES, stream,
                       Ap, Bp, cv, P);
    hipLaunchKernelGGL(k5_final, dim3(1), dim3(256), 0, stream, cd, P, out);
  } else {
    float* u0 = ws;
    float* q  = ws + 4096;
    float* s  = ws + 8192;
    float* cv = ws + 12288;
    hipLaunchKernelGGL(k1_slow, dim3(HH1), dim3(256), 0, stream,
                       W1, x, b1, u0, q, s, out);
    hipLaunchKernelGGL(k2_slow, dim3(HH2), dim3(256), 0, stream,
                       W2, b2, W3, u0, q, cv, out);
    hipLaunchKernelGGL(k4_slow, dim3(DD / 64, HH2 / 64), dim3(256), 0, stream,
                       W2, W1, s, cv, out);
  }
}

// Round 5
// 171.935 us; speedup vs baseline: 1.0178x; 1.0178x over previous
//
#include <hip/hip_runtime.h>
#include <math.h>

#define DD 1024
#define HH1 4096
#define HH2 4096

typedef __attribute__((ext_vector_type(8))) short bf16x8;
typedef __attribute__((ext_vector_type(4))) float f32x4;
typedef unsigned short ushort_t;

// fast-path ws layout (bytes) — total exactly 42,008,576:
//   [0)        u0 (4096 f32)   -- overlaid by P (512 f32) after k0a
//   [16384)    q  (4096 f32)
//   [32768)    cv (4096 f32)
//   [49152)    cd (4096 f32)
//   [65536)    A' = bf16(W2 .* s)  4096x4096 (33554432 B)
//   [33619968) B' = bf16(W1^T)     1024x4096 ( 8388608 B)
#define WS_FAST_BYTES 42008576ull
#define K4_LDS_BYTES (131072 + 64)

__device__ inline void wave_reduce2(float& a, float& b) {
  #pragma unroll
  for (int off = 32; off > 0; off >>= 1) {
    a += __shfl_down(a, off, 64);
    b += __shfl_down(b, off, 64);
  }
}

// fp32 -> bf16 RNE
__device__ inline unsigned int f2b(float f) {
  union { float f; unsigned int u; } v; v.f = f;
  return (v.u + 0x7FFFu + ((v.u >> 16) & 1u)) >> 16;
}
__device__ inline unsigned int pack2(float a, float b) {
  return f2b(a) | (f2b(b) << 16);
}

// async global->LDS, 16 B per lane; lds dst = wave-uniform base + lane*16
__device__ inline void gl_lds16(const void* g, void* l) {
  __builtin_amdgcn_global_load_lds(
      (const __attribute__((address_space(1))) unsigned int*)g,
      (__attribute__((address_space(3))) unsigned int*)l, 16, 0, 0);
}

// kA3: fused layer-1 + W1 transpose-convert (R3-proven). Block = 16 rows.
#define TP2 1032
__global__ __launch_bounds__(256) void kA3_l1t(
    const float* __restrict__ W1, const float* __restrict__ x,
    const float* __restrict__ b1, float* __restrict__ u0,
    float* __restrict__ q, ushort_t* __restrict__ Bp) {
  __shared__ __align__(16) ushort_t T[16 * TP2];  // 33 KB
  const int tid = threadIdx.x;
  const int h0 = blockIdx.x * 16;
  const int r = tid >> 4;          // 0..15 row within block
  const int c = tid & 15;          // 16 threads per row
  const float4* rp = (const float4*)(W1 + (size_t)(h0 + r) * DD);
  const float4* x4 = (const float4*)x;
  float dot = 0.f, sq = 0.f;
  #pragma unroll
  for (int j = 0; j < 16; ++j) {
    const int f = c + j * 16;      // float4 col index 0..255
    float4 wv = rp[f];
    float4 xv = x4[f];
    dot += wv.x * xv.x + wv.y * xv.y + wv.z * xv.z + wv.w * xv.w;
    sq  += wv.x * wv.x + wv.y * wv.y + wv.z * wv.z + wv.w * wv.w;
    uint2 pk;
    pk.x = pack2(wv.x, wv.y);
    pk.y = pack2(wv.z, wv.w);
    *(uint2*)&T[r * TP2 + f * 4] = pk;
  }
  #pragma unroll
  for (int off = 8; off > 0; off >>= 1) {
    dot += __shfl_down(dot, off, 16);
    sq  += __shfl_down(sq, off, 16);
  }
  if (c == 0) {
    float a0 = dot + b1[h0 + r];
    float u = tanhf(a0);
    float s = 1.f - u * u;
    u0[h0 + r] = u;
    q[h0 + r] = -2.f * u * s * sq;
  }
  __syncthreads();
  // transpose out: thread handles i-cols {ip, ip+1} for rep 0,1
  #pragma unroll
  for (int rep = 0; rep < 2; ++rep) {
    const int ip = rep * 512 + tid * 2;
    #pragma unroll
    for (int cg = 0; cg < 2; ++cg) {
      unsigned int R[8];
      #pragma unroll
      for (int r8 = 0; r8 < 8; ++r8)
        R[r8] = *(const unsigned int*)&T[(cg * 8 + r8) * TP2 + ip];
      unsigned int oa[4], ob[4];
      #pragma unroll
      for (int k2 = 0; k2 < 4; ++k2) {
        oa[k2] = (R[2 * k2] & 0xffffu) | (R[2 * k2 + 1] << 16);
        ob[k2] = (R[2 * k2] >> 16) | (R[2 * k2 + 1] & 0xffff0000u);
      }
      *(uint4*)(Bp + (size_t)ip * HH1 + h0 + cg * 8) = *(const uint4*)oa;
      *(uint4*)(Bp + (size_t)(ip + 1) * HH1 + h0 + cg * 8) = *(const uint4*)ob;
    }
  }
}

// k0a v2 (R3-proven): preloaded streaming; z/d dots, A' convert, cv/cd.
__global__ __launch_bounds__(256) void k0a_layer2conv(
    const float* __restrict__ W2, const float* __restrict__ b2,
    const float* __restrict__ W3, const float* __restrict__ u0,
    const float* __restrict__ q, ushort_t* __restrict__ Ap,
    float* __restrict__ cv, float* __restrict__ cd) {
  int g = blockIdx.x;
  int tid = threadIdx.x;
  const float4* row = (const float4*)(W2 + (size_t)g * HH1);
  const float4* u4 = (const float4*)u0;
  const float4* q4 = (const float4*)q;
  float4 w[4], u[4], qq[4];
  #pragma unroll
  for (int it = 0; it < 4; ++it) w[it] = row[tid + it * 256];
  #pragma unroll
  for (int it = 0; it < 4; ++it) u[it] = u4[tid + it * 256];
  #pragma unroll
  for (int it = 0; it < 4; ++it) qq[it] = q4[tid + it * 256];
  float zacc = 0.f, dacc = 0.f;
  #pragma unroll
  for (int it = 0; it < 4; ++it) {
    const int j = tid + it * 256;
    float4 sv;
    sv.x = 1.f - u[it].x * u[it].x;
    sv.y = 1.f - u[it].y * u[it].y;
    sv.z = 1.f - u[it].z * u[it].z;
    sv.w = 1.f - u[it].w * u[it].w;
    zacc += w[it].x * u[it].x + w[it].y * u[it].y +
            w[it].z * u[it].z + w[it].w * u[it].w;
    dacc += w[it].x * qq[it].x + w[it].y * qq[it].y +
            w[it].z * qq[it].z + w[it].w * qq[it].w;
    uint2 pk;
    pk.x = pack2(w[it].x * sv.x, w[it].y * sv.y);
    pk.y = pack2(w[it].z * sv.z, w[it].w * sv.w);
    *(uint2*)(Ap + (size_t)g * HH1 + j * 4) = pk;
  }
  wave_reduce2(zacc, dacc);
  __shared__ float lds[8];
  int lane = tid & 63, wid = tid >> 6;
  if (lane == 0) { lds[wid * 2] = zacc; lds[wid * 2 + 1] = dacc; }
  __syncthreads();
  if (tid == 0) {
    float z = lds[0] + lds[2] + lds[4] + lds[6] + b2[g];
    float d = lds[1] + lds[3] + lds[5] + lds[7];
    float v = tanhf(z);
    float t = 1.f - v * v;
    float c = W3[g] * t;
    cv[g] = c * v;
    cd[g] = c * d;
  }
}

// k4 v5 = proven v2 MINUS the mid-phase barrier (single-variable A/B).
// Theory: the kk==0 barrier forbade pipelining kk=1's ds_reads under
// kk=0's MFMAs, exposing full LDS latency every phase (MfmaUtil 31%).
// Removal is ordering-safe: both phases read buf t&3 (read-only this
// interval); STAGE writes buf (t-1)&3, protected by the top barrier.
__global__ __launch_bounds__(512) void k4_v5(
    const ushort_t* __restrict__ Ap, const ushort_t* __restrict__ Bp,
    const float* __restrict__ cv, float* __restrict__ P) {
  extern __shared__ __align__(16) char smem[];
  char* const Ab0 = smem;              // 4 bufs x 128 rows x 128 B = 65536
  char* const Bb0 = smem + 65536;      // same
  float* const red = (float*)(smem + 131072);

  const int tid = threadIdx.x;
  const int lane = tid & 63;
  const int wave = tid >> 6;           // 0..7
  const int wm = wave >> 1;            // 0..3 -> g quadrant (32 rows)
  const int wn = wave & 1;             // 0..1 -> i half (64 cols)
  const int l = blockIdx.x;            // 0..255
  const int xcd = l & 7;
  const int jj = l >> 3;               // 0..31
  const int g0 = (xcd * 4 + (jj & 3)) * 128;   // XCD owns 4 g-stripes
  const int i0 = (jj >> 2) * 128;

  const int srow = lane >> 3;
  const int schunk = (lane & 7) ^ srow;
  const size_t agbase = (size_t)(g0 + srow) * HH1 + schunk * 8;
  const size_t bgbase = (size_t)(i0 + srow) * HH1 + schunk * 8;

  const int fr = lane & 15;
  const int fc = lane >> 4;
  const int rsw = fr & 7;

  f32x4 acc[2][4];
  const f32x4 zero = {0.f, 0.f, 0.f, 0.f};
  #pragma unroll
  for (int mt = 0; mt < 2; ++mt)
    #pragma unroll
    for (int nt = 0; nt < 4; ++nt) acc[mt][nt] = zero;

  #define STAGE_PAIR(tile, sub) do {                                        \
      const int buf_ = (tile) & 3;                                          \
      const int r0_ = wave * 16 + (sub) * 8;                                \
      const size_t koff_ = (size_t)(((tile) & 63) * 64);                    \
      gl_lds16(Ap + agbase + (size_t)r0_ * HH1 + koff_,                     \
               Ab0 + buf_ * 16384 + r0_ * 128);                             \
      gl_lds16(Bp + bgbase + (size_t)r0_ * HH1 + koff_,                     \
               Bb0 + buf_ * 16384 + r0_ * 128);                             \
    } while (0)

  STAGE_PAIR(0, 0); STAGE_PAIR(0, 1);
  STAGE_PAIR(1, 0); STAGE_PAIR(1, 1);
  STAGE_PAIR(2, 0); STAGE_PAIR(2, 1);

  for (int t = 0; t < 64; ++t) {
    const int buf = t & 3;
    const char* Abuf = Ab0 + buf * 16384;
    const char* Bbuf = Bb0 + buf * 16384;
    asm volatile("s_waitcnt vmcnt(8)" ::: "memory");
    __builtin_amdgcn_s_barrier();
    asm volatile("" ::: "memory");
    #pragma unroll
    for (int kk = 0; kk < 2; ++kk) {
      STAGE_PAIR(t + 3, kk);
      bf16x8 af[2], bfv[4];
      #pragma unroll
      for (int mt = 0; mt < 2; ++mt) {
        const int row = wm * 32 + mt * 16 + fr;
        af[mt] = *(const bf16x8*)(Abuf + row * 128 + (((kk * 4 + fc) ^ rsw) * 16));
      }
      #pragma unroll
      for (int nt = 0; nt < 4; ++nt) {
        const int row = wn * 64 + nt * 16 + fr;
        bfv[nt] = *(const bf16x8*)(Bbuf + row * 128 + (((kk * 4 + fc) ^ rsw) * 16));
      }
      __builtin_amdgcn_s_setprio(1);
      #pragma unroll
      for (int mt = 0; mt < 2; ++mt)
        #pragma unroll
        for (int nt = 0; nt < 4; ++nt)
          acc[mt][nt] = __builtin_amdgcn_mfma_f32_16x16x32_bf16(
              af[mt], bfv[nt], acc[mt][nt], 0, 0, 0);
      __builtin_amdgcn_s_setprio(0);
      // (mid-phase barrier removed — v5's single change vs proven v2)
    }
    asm volatile("" ::: "memory");
    __builtin_amdgcn_s_barrier();
  }
  #undef STAGE_PAIR

  float part = 0.f;
  #pragma unroll
  for (int mt = 0; mt < 2; ++mt) {
    #pragma unroll
    for (int r = 0; r < 4; ++r) {
      const int g = g0 + wm * 32 + mt * 16 + fc * 4 + r;
      const float c = cv[g];
      float ss = 0.f;
      #pragma unroll
      for (int nt = 0; nt < 4; ++nt) {
        float v = acc[mt][nt][r];
        ss += v * v;
      }
      part += c * ss;
    }
  }
  #pragma unroll
  for (int off = 32; off > 0; off >>= 1) part += __shfl_down(part, off, 64);
  if (lane == 0) red[wave] = part;
  __syncthreads();  // also drains the wrap-stage loads
  if (tid == 0) {
    float s = 0.f;
    #pragma unroll
    for (int w2 = 0; w2 < 8; ++w2) s += red[w2];
    P[l] = s;
  }
}

// k5: out[0] = Σ cd - 2 Σ P. Plain store (no atomics, no zero-init needed).
__global__ __launch_bounds__(256) void k5_final(
    const float* __restrict__ cd, const float* __restrict__ P,
    float* __restrict__ out) {
  int tid = threadIdx.x;
  float a = 0.f;
  for (int j = tid; j < HH2; j += 256) a += cd[j];
  float b = P[tid];  // k4 grid = 256
  float v = a - 2.f * b;
  #pragma unroll
  for (int off = 32; off > 0; off >>= 1) v += __shfl_down(v, off, 64);
  __shared__ float lds[4];
  int lane = tid & 63, wid = tid >> 6;
  if (lane == 0) lds[wid] = v;
  __syncthreads();
  if (tid == 0) out[0] = lds[0] + lds[1] + lds[2] + lds[3];
}

// ---------------- fallback (fp32, ws = 64 KB only; R1-proven) ----------------

__global__ __launch_bounds__(256) void k1_slow(
    const float* __restrict__ W1, const float* __restrict__ x,
    const float* __restrict__ b1, float* __restrict__ u0,
    float* __restrict__ q, float* __restrict__ s_out,
    float* __restrict__ out) {
  int h = blockIdx.x;
  int tid = threadIdx.x;
  const float4* row = (const float4*)(W1 + (size_t)h * DD);
  const float4* x4 = (const float4*)x;
  float4 w = row[tid];
  float4 xv = x4[tid];
  float dot = w.x * xv.x + w.y * xv.y + w.z * xv.z + w.w * xv.w;
  float sq = w.x * w.x + w.y * w.y + w.z * w.z + w.w * w.w;
  wave_reduce2(dot, sq);
  __shared__ float lds[8];
  int lane = tid & 63, wid = tid >> 6;
  if (lane == 0) { lds[wid * 2] = dot; lds[wid * 2 + 1] = sq; }
  __syncthreads();
  if (tid == 0) {
    float dsum = lds[0] + lds[2] + lds[4] + lds[6];
    float rsum = lds[1] + lds[3] + lds[5] + lds[7];
    float a0 = dsum + b1[h];
    float u = tanhf(a0);
    float s = 1.f - u * u;
    u0[h] = u;
    s_out[h] = s;
    q[h] = -2.f * u * s * rsum;
    if (h == 0) out[0] = 0.f;
  }
}

__global__ __launch_bounds__(256) void k2_slow(
    const float* __restrict__ W2, const float* __restrict__ b2,
    const float* __restrict__ W3, const float* __restrict__ u0,
    const float* __restrict__ q, float* __restrict__ cv,
    float* __restrict__ out) {
  int g = blockIdx.x;
  int tid = threadIdx.x;
  const float4* row = (const float4*)(W2 + (size_t)g * HH1);
  const float4* u4 = (const float4*)u0;
  const float4* q4 = (const float4*)q;
  float zacc = 0.f, dacc = 0.f;
  for (int j = tid; j < HH1 / 4; j += 256) {
    float4 w = row[j];
    float4 u = u4[j];
    float4 qq = q4[j];
    zacc += w.x * u.x + w.y * u.y + w.z * u.z + w.w * u.w;
    dacc += w.x * qq.x + w.y * qq.y + w.z * qq.z + w.w * qq.w;
  }
  wave_reduce2(zacc, dacc);
  __shared__ float lds[8];
  int lane = tid & 63, wid = tid >> 6;
  if (lane == 0) { lds[wid * 2] = zacc; lds[wid * 2 + 1] = dacc; }
  __syncthreads();
  if (tid == 0) {
    float z = lds[0] + lds[2] + lds[4] + lds[6] + b2[g];
    float d = lds[1] + lds[3] + lds[5] + lds[7];
    float v = tanhf(z);
    float t = 1.f - v * v;
    float c = W3[g] * t;
    cv[g] = c * v;
    atomicAdd(out, c * d);
  }
}

__global__ __launch_bounds__(256) void k4_slow(
    const float* __restrict__ W2, const float* __restrict__ W1,
    const float* __restrict__ s, const float* __restrict__ cv,
    float* __restrict__ out) {
  __shared__ float As[32][68];
  __shared__ float Bs[32][68];
  int tid = threadIdx.x;
  int g0 = blockIdx.y * 64;
  int i0 = blockIdx.x * 64;
  int tr = (tid / 16) * 4;
  int tc = (tid % 16) * 4;
  float acc[4][4] = {};
  for (int k0 = 0; k0 < HH1; k0 += 32) {
    for (int ll = tid; ll < (64 * 32 / 4); ll += 256) {
      int row = ll / 8;
      int c4 = ll % 8;
      float4 w = *(const float4*)(W2 + (size_t)(g0 + row) * HH1 + k0 + c4 * 4);
      float4 sv = *(const float4*)(s + k0 + c4 * 4);
      As[c4 * 4 + 0][row] = w.x * sv.x;
      As[c4 * 4 + 1][row] = w.y * sv.y;
      As[c4 * 4 + 2][row] = w.z * sv.z;
      As[c4 * 4 + 3][row] = w.w * sv.w;
    }
    for (int ll = tid; ll < (32 * 64 / 4); ll += 256) {
      int row = ll / 16;
      int c4 = ll % 16;
      float4 w = *(const float4*)(W1 + (size_t)(k0 + row) * DD + i0 + c4 * 4);
      *(float4*)&Bs[row][c4 * 4] = w;
    }
    __syncthreads();
    #pragma unroll
    for (int k = 0; k < 32; ++k) {
      float4 av = *(const float4*)&As[k][tr];
      float4 bv = *(const float4*)&Bs[k][tc];
      float a_[4] = {av.x, av.y, av.z, av.w};
      float b_[4] = {bv.x, bv.y, bv.z, bv.w};
      #pragma unroll
      for (int r = 0; r < 4; ++r)
        #pragma unroll
        for (int c = 0; c < 4; ++c)
          acc[r][c] += a_[r] * b_[c];
    }
    __syncthreads();
  }
  float contrib = 0.f;
  #pragma unroll
  for (int r = 0; r < 4; ++r) {
    float ss = acc[r][0] * acc[r][0] + acc[r][1] * acc[r][1] +
               acc[r][2] * acc[r][2] + acc[r][3] * acc[r][3];
    contrib += cv[g0 + tr + r] * ss;
  }
  #pragma unroll
  for (int off = 32; off > 0; off >>= 1) contrib += __shfl_down(contrib, off, 64);
  __shared__ float red[4];
  int lane = tid & 63, wid = tid >> 6;
  if (lane == 0) red[wid] = contrib;
  __syncthreads();
  if (tid == 0) atomicAdd(out, -2.f * (red[0] + red[1] + red[2] + red[3]));
}

extern "C" void kernel_launch(void* const* d_in, const int* in_sizes, int n_in,
                              void* d_out, int out_size, void* d_ws, size_t ws_size,
                              hipStream_t stream) {
  const float* x  = (const float*)d_in[0];
  const float* W1 = (const float*)d_in[1];
  const float* b1 = (const float*)d_in[2];
  const float* W2 = (const float*)d_in[3];
  const float* b2 = (const float*)d_in[4];
  const float* W3 = (const float*)d_in[5];
  // b3 (d_in[6]) vanishes under the Laplacian.
  float* out = (float*)d_out;
  float* ws = (float*)d_ws;

  if (ws_size >= WS_FAST_BYTES) {
    float* u0 = ws;              // overlaid by P after k0a completes
    float* q  = ws + 4096;
    float* cv = ws + 8192;
    float* cd = ws + 12288;
    float* P  = ws;              // 256 floats, k4 -> k5
    ushort_t* Ap = (ushort_t*)((char*)d_ws + 65536);
    ushort_t* Bp = (ushort_t*)((char*)d_ws + 33619968);
    hipFuncSetAttribute((const void*)k4_v5,
                        hipFuncAttributeMaxDynamicSharedMemorySize,
                        K4_LDS_BYTES);
    hipLaunchKernelGGL(kA3_l1t, dim3(256), dim3(256), 0, stream,
                       W1, x, b1, u0, q, Bp);
    hipLaunchKernelGGL(k0a_layer2conv, dim3(HH2), dim3(256), 0, stream,
                       W2, b2, W3, u0, q, Ap, cv, cd);
    hipLaunchKernelGGL(k4_v5, dim3(256), dim3(512), K4_LDS_BYTES, stream,
                       Ap, Bp, cv, P);
    hipLaunchKernelGGL(k5_final, dim3(1), dim3(256), 0, stream, cd, P, out);
  } else {
    float* u0 = ws;
    float* q  = ws + 4096;
    float* s  = ws + 8192;
    float* cv = ws + 12288;
    hipLaunchKernelGGL(k1_slow, dim3(HH1), dim3(256), 0, stream,
                       W1, x, b1, u0, q, s, out);
    hipLaunchKernelGGL(k2_slow, dim3(HH2), dim3(256), 0, stream,
                       W2, b2, W3, u0, q, cv, out);
    hipLaunchKernelGGL(k4_slow, dim3(DD / 64, HH2 / 64), dim3(256), 0, stream,
                       W2, W1, s, cv, out);
  }
}